// Round 14
// baseline (63.079 us; speedup 1.0000x reference)
//
#include <hip/hip_runtime.h>
#include <hip/hip_bf16.h>
#include <cstddef>

// B=8, L=1024, E=1024, H=8, d=128
// out = BandedGaussianAttn(values @ Win^T) @ Wout^T
// Identity (R4..R13-proven): equal stds -> smoothing commutes with projection;
// per-head offset = row shift of GEMM1's A operand (BN=128 == one head).
// Pipeline:
//   smooth_lds: R13-exact async-staged 9-tap smoother (fp32->bf16) + weight cvt
//   GEMM1/GEMM2: NEW 32x32x16-MFMA single-phase pipe (1 barrier/K-tile)

#define BATCH 8
#define SEQL  1024
#define EMB   1024
#define VROWS 1056   // 33 x 32; VG row r holds smoothed source p = r-4

typedef unsigned short u16;
typedef __attribute__((ext_vector_type(8))) short s16x8;
typedef __attribute__((ext_vector_type(4))) float f32x4;
typedef __attribute__((ext_vector_type(16))) float f32x16;
typedef __attribute__((ext_vector_type(8))) unsigned short u16x8;
typedef __attribute__((ext_vector_type(4))) unsigned short u16x4;

#define GLOAD_LDS16(g, l)                                                     \
    __builtin_amdgcn_global_load_lds(                                         \
        (const __attribute__((address_space(1))) void*)(g),                   \
        (__attribute__((address_space(3))) void*)(l), 16, 0, 0)

__device__ __forceinline__ u16 f2bf(float f) {
    unsigned u = __builtin_bit_cast(unsigned, f);
    u += 0x7FFF + ((u >> 16) & 1);
    return (u16)(u >> 16);
}

__constant__ int c_ofs[8] = { -3, -2, -1, 0, 0, 1, 2, 3 };

// ---------- smooth_lds: R13-exact ----------
__global__ __launch_bounds__(256) void smooth_lds(
    const float* __restrict__ values, const unsigned char* __restrict__ mask,
    const float* __restrict__ wi, const float* __restrict__ wo,
    u16* __restrict__ VG, u16* __restrict__ wib, u16* __restrict__ wob)
{
    constexpr float W[9] = {
        1.3383022576488537e-04f, 4.431848411938008e-03f, 5.399096651318806e-02f,
        2.4197072451914337e-01f, 3.989422804014327e-01f, 2.4197072451914337e-01f,
        5.399096651318806e-02f,  4.431848411938008e-03f, 1.3383022576488537e-04f
    };
    __shared__ float sx[40 * 256];
    __shared__ float smf[40];

    const int blk = blockIdx.x;
    const int NSM = BATCH * 33 * 4;    // 1056
    const int tid = threadIdx.x;
    if (blk < NSM) {
        const int b  = blk & 7;
        const int t  = blk >> 3;
        const int g  = t >> 2;
        const int cg = t & 3;
        const int r0 = g * 32;
        const int v0 = r0 - 8;
        const int c0 = cg * 256;
        const float* vbase = values + (size_t)b * SEQL * EMB + c0;
        const unsigned char* mrow = mask + b * SEQL;

        #pragma unroll
        for (int c = 0; c < 10; ++c) {
            const int n    = c * 256 + tid;
            const int row  = n >> 6;
            const int col4 = (n & 63) * 4;
            const int v    = v0 + row;
            const int vc   = v < 0 ? 0 : (v > SEQL - 1 ? SEQL - 1 : v);
            GLOAD_LDS16(vbase + (size_t)vc * EMB + col4,
                        sx + c * 1024 + (tid >> 6) * 256);
        }
        if (tid < 40) {
            const int v  = v0 + tid;
            const int vc = v < 0 ? 0 : (v > SEQL - 1 ? SEQL - 1 : v);
            smf[tid] = ((unsigned)v < (unsigned)SEQL && !mrow[vc]) ? 1.f : 0.f;
        }
        asm volatile("s_waitcnt vmcnt(0)" ::: "memory");
        __syncthreads();

        const int rg = tid >> 6;
        const int cc = tid & 63;
        const int rl0 = rg * 8;
        f32x4 acc[8] = {};
        #pragma unroll
        for (int i = 0; i < 16; ++i) {
            const f32x4 xr = *(const f32x4*)&sx[(rl0 + i) * 256 + cc * 4];
            const float f = smf[rl0 + i];
            const float x0 = xr[0] * f, x1 = xr[1] * f, x2 = xr[2] * f, x3 = xr[3] * f;
            #pragma unroll
            for (int k = 0; k < 8; ++k) {
                const int j = i - k;
                if (j < 0 || j > 8) continue;
                const float w = W[j];
                acc[k][0] = fmaf(w, x0, acc[k][0]);
                acc[k][1] = fmaf(w, x1, acc[k][1]);
                acc[k][2] = fmaf(w, x2, acc[k][2]);
                acc[k][3] = fmaf(w, x3, acc[k][3]);
            }
        }
        u16* og = VG + (size_t)(b * VROWS + r0 + rl0) * EMB + c0 + cc * 4;
        #pragma unroll
        for (int k = 0; k < 8; ++k) {
            u16x4 o;
            o[0] = f2bf(acc[k][0]); o[1] = f2bf(acc[k][1]);
            o[2] = f2bf(acc[k][2]); o[3] = f2bf(acc[k][3]);
            *(u16x4*)(og + (size_t)k * EMB) = o;
        }
    } else {
        const int k = (blk - NSM) * 256 + tid;
        const float* src = (k < 131072) ? wi : wo;
        u16* dst = (k < 131072) ? wib : wob;
        const size_t off = (size_t)(k & 131071) * 8;
        const float4 a = *(const float4*)(src + off);
        const float4 b4 = *(const float4*)(src + off + 4);
        u16x8 o;
        o[0] = f2bf(a.x);  o[1] = f2bf(a.y);  o[2] = f2bf(a.z);  o[3] = f2bf(a.w);
        o[4] = f2bf(b4.x); o[5] = f2bf(b4.y); o[6] = f2bf(b4.z); o[7] = f2bf(b4.w);
        *(u16x8*)(dst + off) = o;
    }
}

// ---------- GEMM v2: 32x32x16 MFMA, single-phase pipe ----------
// C[M,N] = A[M,K]*B[N,K]^T. BM=256 BN=128 BK=64, 512 thr / 8 waves (4Mx2N,
// per-wave 64x64 = 2x2 frags of 32x32). 3-buffer LDS, ONE barrier per K-tile:
//   reads(t) -> stage(t+2) -> vmcnt(6) -> lgkm(0) -> 16 MFMA -> barrier
// Hazard proof: reader's lgkmcnt(0) precedes its MFMA precedes the barrier,
// so by the time any wave passes barrier(t) and stages into buffer t%3
// (= (t+3)%3), every wave's reads of t are complete. Residency: vmcnt(6)@t
// drains the 6 loads issued @t-1 for tile t+1; barrier joins all waves.
constexpr int BM = 256, BN = 128, BK = 64;
constexpr int A_EL = BM * BK;
constexpr int B_EL = BN * BK;
constexpr int BUF_EL = A_EL + B_EL;      // 48 KB x3 = 144 KB

template <bool OUT_BF16, bool SHIFTED>
__global__ __launch_bounds__(512, 2) void gemm_nt_pipe(
    const u16* __restrict__ A, const u16* __restrict__ B,
    void* __restrict__ Cout, int M, int N, int K)
{
    __shared__ u16 lds[3 * BUF_EL];

    const int tid  = threadIdx.x;
    const int lane = tid & 63;
    const int wave = tid >> 6;

    const int nwg = gridDim.x;
    const int bid = blockIdx.x;
    const int swz = (bid & 7) * (nwg >> 3) + (bid >> 3);   // T1 (nwg%8==0)
    const int ntn = N >> 7;
    const int row0 = (swz / ntn) * BM;
    const int col0 = (swz % ntn) * BN;

    int arow0;
    if (SHIFTED) {
        const int b  = row0 >> 10;            // BM=256 | 1024: no batch straddle
        const int q0 = row0 & (SEQL - 1);
        arow0 = b * VROWS + q0 + 4 + c_ofs[col0 >> 7];
    } else {
        arow0 = row0;
    }
    const u16* Ab = A + (size_t)arow0 * K;
    const u16* Bb = B + (size_t)col0 * K;

    const int wm  = wave >> 1;    // 0..3 (M quarter)
    const int wn  = wave & 1;     // 0..1 (N half)
    const int l31 = lane & 31;
    const int lhi = lane >> 5;    // 0..1

    const int srow   = tid >> 3;
    const int schunk = tid & 7;

    f32x16 acc[2][2] = {};

    auto stageAll = [&](int bsel, int kt) {
        u16* Abuf = lds + bsel * BUF_EL;
        u16* Bbuf = Abuf + A_EL;
        const int k0 = kt << 6;
        #pragma unroll
        for (int c = 0; c < 4; ++c) {
            const int row = c * 64 + srow;
            const int sc  = (schunk ^ (row & 7)) << 3;     // T2 involution
            GLOAD_LDS16(Ab + (size_t)row * K + k0 + sc, Abuf + c * 4096 + wave * 512);
        }
        #pragma unroll
        for (int c = 0; c < 2; ++c) {
            const int row = c * 64 + srow;
            const int sc  = (schunk ^ (row & 7)) << 3;
            GLOAD_LDS16(Bb + (size_t)row * K + k0 + sc, Bbuf + c * 4096 + wave * 512);
        }
    };

    auto doTile = [&](int tile, int mode /*0: stage+vm6, 1: vm0, 2: none*/) {
        const u16* Abuf = lds + (tile % 3) * BUF_EL;
        const u16* Bbuf = Abuf + A_EL;
        s16x8 a[2][4], b[2][4];
        #pragma unroll
        for (int ks = 0; ks < 4; ++ks) {
            const int cb = ks * 2 + lhi;                   // k-chunk index
            #pragma unroll
            for (int m = 0; m < 2; ++m) {
                const int row = wm * 64 + m * 32 + l31;
                a[m][ks] = *(const s16x8*)(Abuf + row * 64 + ((cb ^ (row & 7)) << 3));
            }
            #pragma unroll
            for (int n = 0; n < 2; ++n) {
                const int row = wn * 64 + n * 32 + l31;
                b[n][ks] = *(const s16x8*)(Bbuf + row * 64 + ((cb ^ (row & 7)) << 3));
            }
        }
        if (mode == 0) {
            stageAll((tile + 2) % 3, tile + 2);
            asm volatile("s_waitcnt vmcnt(6)" ::: "memory");   // tile+1 resident
        } else if (mode == 1) {
            asm volatile("s_waitcnt vmcnt(0)" ::: "memory");   // all resident
        }
        asm volatile("s_waitcnt lgkmcnt(0)" ::: "memory");
        __builtin_amdgcn_sched_barrier(0);                     // rule #18 fence
        __builtin_amdgcn_s_setprio(1);
        #pragma unroll
        for (int ks = 0; ks < 4; ++ks)
            #pragma unroll
            for (int m = 0; m < 2; ++m)
                #pragma unroll
                for (int n = 0; n < 2; ++n)
                    acc[m][n] = __builtin_amdgcn_mfma_f32_32x32x16_bf16(
                        a[m][ks], b[n][ks], acc[m][n], 0, 0, 0);
        __builtin_amdgcn_s_setprio(0);
        __builtin_amdgcn_s_barrier();
    };

    const int NT = K >> 6;               // 16

    stageAll(0, 0);
    stageAll(1, 1);
    asm volatile("s_waitcnt vmcnt(6)" ::: "memory");   // tile 0 resident
    __builtin_amdgcn_s_barrier();

    for (int t = 0; t < NT - 2; ++t) doTile(t, 0);
    doTile(NT - 2, 1);
    doTile(NT - 1, 2);

    // 32x32 C/D layout (m74/m101): col = lane&31, row = (r&3) + 8*(r>>2) + 4*(lane>>5)
    const int crow_b = row0 + wm * 64 + 4 * lhi;
    const int ccol_b = col0 + wn * 64 + l31;
    if (OUT_BF16) {
        u16* C = (u16*)Cout;
        #pragma unroll
        for (int m = 0; m < 2; ++m)
            #pragma unroll
            for (int n = 0; n < 2; ++n)
                #pragma unroll
                for (int r = 0; r < 16; ++r)
                    C[(size_t)(crow_b + m * 32 + (r & 3) + 8 * (r >> 2)) * N
                      + ccol_b + n * 32] = f2bf(acc[m][n][r]);
    } else {
        float* C = (float*)Cout;
        #pragma unroll
        for (int m = 0; m < 2; ++m)
            #pragma unroll
            for (int n = 0; n < 2; ++n)
                #pragma unroll
                for (int r = 0; r < 16; ++r)
                    C[(size_t)(crow_b + m * 32 + (r & 3) + 8 * (r >> 2)) * N
                      + ccol_b + n * 32] = acc[m][n][r];
    }
}

extern "C" void kernel_launch(void* const* d_in, const int* in_sizes, int n_in,
                              void* d_out, int out_size, void* d_ws, size_t ws_size,
                              hipStream_t stream) {
    const float* values = (const float*)d_in[0];
    // d_in[1] = queries: only its length matters (Lq == L)
    const unsigned char* mask = (const unsigned char*)d_in[2];
    const float* Win  = (const float*)d_in[3];
    const float* Wout = (const float*)d_in[4];
    float* out = (float*)d_out;

    const int M = BATCH * SEQL;   // 8192
    const int N = EMB;            // 1024
    const int K = EMB;            // 1024

    u16* VG    = (u16*)d_ws;                              // 8*1056*1024 (17.3 MB)
    u16* Attb  = VG + (size_t)BATCH * VROWS * EMB;        // 16 MB
    u16* Winb  = Attb + (size_t)M * EMB;                  // 2 MB
    u16* Woutb = Winb + (size_t)EMB * EMB;                // 2 MB (~37 MB total)

    smooth_lds<<<1056 + 1024, 256, 0, stream>>>(
        values, mask, Win, Wout, VG, Winb, Woutb);

    dim3 ggrid((M / BM) * (N / BN));   // 256 WGs
    gemm_nt_pipe<true,  true ><<<ggrid, 512, 0, stream>>>(VG,   Winb,  Attb, M, N, K);
    gemm_nt_pipe<false, false><<<ggrid, 512, 0, stream>>>(Attb, Woutb, out,  M, N, K);
}

// Round 15
// 63.063 us; speedup vs baseline: 1.0003x; 1.0003x over previous
//
#include <hip/hip_runtime.h>
#include <hip/hip_bf16.h>
#include <cstddef>

// B=8, L=1024, E=1024, H=8, d=128
// out = BandedGaussianAttn(values @ Win^T) @ Wout^T
// Identity (R4..R13-proven): equal stds -> smoothing commutes with projection;
// per-head offset = row shift of GEMM1's A operand (BN=128 == one head).
// Pipeline:
//   smooth_lds: R13-exact async-staged 9-tap smoother (fp32->bf16) + weight cvt
//   GEMM v3: 128x128 tile, BK=32, 3-buffer (48KB -> 2 blocks/CU), 256thr/4waves,
//            counted vmcnt(4), T2 XOR ((row>>1)&3), T5 setprio, T1 XCD swizzle

#define BATCH 8
#define SEQL  1024
#define EMB   1024
#define VROWS 1056   // 33 x 32; VG row r holds smoothed source p = r-4

typedef unsigned short u16;
typedef __attribute__((ext_vector_type(8))) short s16x8;
typedef __attribute__((ext_vector_type(4))) float f32x4;
typedef __attribute__((ext_vector_type(8))) unsigned short u16x8;
typedef __attribute__((ext_vector_type(4))) unsigned short u16x4;

#define GLOAD_LDS16(g, l)                                                     \
    __builtin_amdgcn_global_load_lds(                                         \
        (const __attribute__((address_space(1))) void*)(g),                   \
        (__attribute__((address_space(3))) void*)(l), 16, 0, 0)

__device__ __forceinline__ u16 f2bf(float f) {
    unsigned u = __builtin_bit_cast(unsigned, f);
    u += 0x7FFF + ((u >> 16) & 1);
    return (u16)(u >> 16);
}

__constant__ int c_ofs[8] = { -3, -2, -1, 0, 0, 1, 2, 3 };

// ---------- smooth_lds: R13-exact ----------
__global__ __launch_bounds__(256) void smooth_lds(
    const float* __restrict__ values, const unsigned char* __restrict__ mask,
    const float* __restrict__ wi, const float* __restrict__ wo,
    u16* __restrict__ VG, u16* __restrict__ wib, u16* __restrict__ wob)
{
    constexpr float W[9] = {
        1.3383022576488537e-04f, 4.431848411938008e-03f, 5.399096651318806e-02f,
        2.4197072451914337e-01f, 3.989422804014327e-01f, 2.4197072451914337e-01f,
        5.399096651318806e-02f,  4.431848411938008e-03f, 1.3383022576488537e-04f
    };
    __shared__ float sx[40 * 256];
    __shared__ float smf[40];

    const int blk = blockIdx.x;
    const int NSM = BATCH * 33 * 4;    // 1056
    const int tid = threadIdx.x;
    if (blk < NSM) {
        const int b  = blk & 7;
        const int t  = blk >> 3;
        const int g  = t >> 2;
        const int cg = t & 3;
        const int r0 = g * 32;
        const int v0 = r0 - 8;
        const int c0 = cg * 256;
        const float* vbase = values + (size_t)b * SEQL * EMB + c0;
        const unsigned char* mrow = mask + b * SEQL;

        #pragma unroll
        for (int c = 0; c < 10; ++c) {
            const int n    = c * 256 + tid;
            const int row  = n >> 6;
            const int col4 = (n & 63) * 4;
            const int v    = v0 + row;
            const int vc   = v < 0 ? 0 : (v > SEQL - 1 ? SEQL - 1 : v);
            GLOAD_LDS16(vbase + (size_t)vc * EMB + col4,
                        sx + c * 1024 + (tid >> 6) * 256);
        }
        if (tid < 40) {
            const int v  = v0 + tid;
            const int vc = v < 0 ? 0 : (v > SEQL - 1 ? SEQL - 1 : v);
            smf[tid] = ((unsigned)v < (unsigned)SEQL && !mrow[vc]) ? 1.f : 0.f;
        }
        asm volatile("s_waitcnt vmcnt(0)" ::: "memory");
        __syncthreads();

        const int rg = tid >> 6;
        const int cc = tid & 63;
        const int rl0 = rg * 8;
        f32x4 acc[8] = {};
        #pragma unroll
        for (int i = 0; i < 16; ++i) {
            const f32x4 xr = *(const f32x4*)&sx[(rl0 + i) * 256 + cc * 4];
            const float f = smf[rl0 + i];
            const float x0 = xr[0] * f, x1 = xr[1] * f, x2 = xr[2] * f, x3 = xr[3] * f;
            #pragma unroll
            for (int k = 0; k < 8; ++k) {
                const int j = i - k;
                if (j < 0 || j > 8) continue;
                const float w = W[j];
                acc[k][0] = fmaf(w, x0, acc[k][0]);
                acc[k][1] = fmaf(w, x1, acc[k][1]);
                acc[k][2] = fmaf(w, x2, acc[k][2]);
                acc[k][3] = fmaf(w, x3, acc[k][3]);
            }
        }
        u16* og = VG + (size_t)(b * VROWS + r0 + rl0) * EMB + c0 + cc * 4;
        #pragma unroll
        for (int k = 0; k < 8; ++k) {
            u16x4 o;
            o[0] = f2bf(acc[k][0]); o[1] = f2bf(acc[k][1]);
            o[2] = f2bf(acc[k][2]); o[3] = f2bf(acc[k][3]);
            *(u16x4*)(og + (size_t)k * EMB) = o;
        }
    } else {
        const int k = (blk - NSM) * 256 + tid;
        const float* src = (k < 131072) ? wi : wo;
        u16* dst = (k < 131072) ? wib : wob;
        const size_t off = (size_t)(k & 131071) * 8;
        const float4 a = *(const float4*)(src + off);
        const float4 b4 = *(const float4*)(src + off + 4);
        u16x8 o;
        o[0] = f2bf(a.x);  o[1] = f2bf(a.y);  o[2] = f2bf(a.z);  o[3] = f2bf(a.w);
        o[4] = f2bf(b4.x); o[5] = f2bf(b4.y); o[6] = f2bf(b4.z); o[7] = f2bf(b4.w);
        *(u16x8*)(dst + off) = o;
    }
}

// ---------- GEMM v3: C[M,N] = A[M,K]*B[N,K]^T ----------
// BM=BN=128, BK=32, 256 thr / 4 waves (2Mx2N, per-wave 64x64 of 16x16x32).
// 3-buffer LDS (48KB -> 2 blocks/CU co-resident: cross-block overlap hides
// barrier/stage stalls). Pipeline per half-tile h:
//   ds_read(h) -> stage(h+2) -> vmcnt(4) -> bar -> lgkm(0) -> 16 MFMA -> bar
// Residency: vmcnt(4) leaves only h+2's 4 loads outstanding => h+1 resident.
// WAR: reads(h-1) complete (lgkm) before MFMA(h-1) before bar(h-1), and
// stage(h+2) [same buffer as h-1] is issued after that bar.
// T2: 64B rows -> XOR chunk with (row>>1)&3 (both sides) => 2-way-free ds_read.
constexpr int BM = 128, BN = 128, BK = 32;
constexpr int A_EL = BM * BK;            // 4096 elems, 8 KB
constexpr int B_EL = BN * BK;            // 8 KB
constexpr int BUF_EL = A_EL + B_EL;      // 16 KB x3 = 48 KB

template <bool OUT_BF16, bool SHIFTED>
__global__ __launch_bounds__(256, 2) void gemm_nt_pipe(
    const u16* __restrict__ A, const u16* __restrict__ B,
    void* __restrict__ Cout, int M, int N, int K)
{
    __shared__ u16 lds[3 * BUF_EL];

    const int tid  = threadIdx.x;
    const int lane = tid & 63;
    const int wave = tid >> 6;

    const int nwg = gridDim.x;                 // 512, %8==0
    const int bid = blockIdx.x;
    const int swz = (bid & 7) * (nwg >> 3) + (bid >> 3);   // T1 bijective
    const int ntn = N >> 7;                    // 8
    const int row0 = (swz / ntn) * BM;
    const int col0 = (swz % ntn) * BN;

    int arow0;
    if (SHIFTED) {
        const int b  = row0 >> 10;             // BM=128 | 1024: no batch straddle
        const int q0 = row0 & (SEQL - 1);
        arow0 = b * VROWS + q0 + 4 + c_ofs[col0 >> 7];
    } else {
        arow0 = row0;
    }
    const u16* Ab = A + (size_t)arow0 * K;
    const u16* Bb = B + (size_t)col0 * K;

    const int wm = wave >> 1;                  // 0..1
    const int wn = wave & 1;                   // 0..1
    const int fr = lane & 15;
    const int fg = lane >> 4;                  // 0..3 = k-chunk

    f32x4 acc[4][4] = {};

    // stage half-tile ht into buffer bsel: LDS(row, c) <- global(row, c^((row>>1)&3))
    auto stage = [&](int bsel, int ht) {
        u16* Abuf = lds + bsel * BUF_EL;
        u16* Bbuf = Abuf + A_EL;
        const int k0 = ht << 5;
        #pragma unroll
        for (int i = 0; i < 2; ++i) {
            const int n   = i * 256 + tid;     // chunk id
            const int row = n >> 2;            // 0..127
            const int c   = n & 3;
            const int sc  = (c ^ ((row >> 1) & 3)) << 3;
            GLOAD_LDS16(Ab + (size_t)row * K + k0 + sc,
                        Abuf + i * 2048 + wave * 512);
        }
        #pragma unroll
        for (int i = 0; i < 2; ++i) {
            const int n   = i * 256 + tid;
            const int row = n >> 2;
            const int c   = n & 3;
            const int sc  = (c ^ ((row >> 1) & 3)) << 3;
            GLOAD_LDS16(Bb + (size_t)row * K + k0 + sc,
                        Bbuf + i * 2048 + wave * 512);
        }
    };

    auto doHalf = [&](int ht, int mode /*0: stage+vm4, 1: vm0, 2: none*/) {
        const u16* Abuf = lds + (ht % 3) * BUF_EL;
        const u16* Bbuf = Abuf + A_EL;
        s16x8 af[4], bf[4];
        #pragma unroll
        for (int m = 0; m < 4; ++m) {
            const int row = wm * 64 + m * 16 + fr;
            const int cb  = fg ^ ((row >> 1) & 3);
            af[m] = *(const s16x8*)(Abuf + row * 32 + cb * 8);
        }
        #pragma unroll
        for (int n = 0; n < 4; ++n) {
            const int row = wn * 64 + n * 16 + fr;
            const int cb  = fg ^ ((row >> 1) & 3);
            bf[n] = *(const s16x8*)(Bbuf + row * 32 + cb * 8);
        }
        if (mode == 0) {
            stage((ht + 2) % 3, ht + 2);
            asm volatile("s_waitcnt vmcnt(4)" ::: "memory");   // ht+1 resident
        } else if (mode == 1) {
            asm volatile("s_waitcnt vmcnt(0)" ::: "memory");
        }
        __builtin_amdgcn_s_barrier();
        asm volatile("s_waitcnt lgkmcnt(0)" ::: "memory");
        __builtin_amdgcn_sched_barrier(0);                     // rule #18 fence
        __builtin_amdgcn_s_setprio(1);
        #pragma unroll
        for (int m = 0; m < 4; ++m)
            #pragma unroll
            for (int n = 0; n < 4; ++n)
                acc[m][n] = __builtin_amdgcn_mfma_f32_16x16x32_bf16(
                    af[m], bf[n], acc[m][n], 0, 0, 0);
        __builtin_amdgcn_s_setprio(0);
        __builtin_amdgcn_s_barrier();
    };

    const int NH = K >> 5;                     // 32 half-tiles

    stage(0, 0);
    stage(1, 1);
    asm volatile("s_waitcnt vmcnt(4)" ::: "memory");   // half-tile 0 resident
    __builtin_amdgcn_s_barrier();

    for (int h = 0; h < NH - 2; ++h) doHalf(h, 0);
    doHalf(NH - 2, 1);
    doHalf(NH - 1, 2);

    // C/D layout (m89): col = lane&15, row = fg*4 + j
    const int crow0 = row0 + wm * 64 + fg * 4;
    const int ccol0 = col0 + wn * 64 + fr;
    if (OUT_BF16) {
        u16* C = (u16*)Cout;
        #pragma unroll
        for (int m = 0; m < 4; ++m)
            #pragma unroll
            for (int n = 0; n < 4; ++n)
                #pragma unroll
                for (int j = 0; j < 4; ++j)
                    C[(size_t)(crow0 + m * 16 + j) * N + ccol0 + n * 16] =
                        f2bf(acc[m][n][j]);
    } else {
        float* C = (float*)Cout;
        #pragma unroll
        for (int m = 0; m < 4; ++m)
            #pragma unroll
            for (int n = 0; n < 4; ++n)
                #pragma unroll
                for (int j = 0; j < 4; ++j)
                    C[(size_t)(crow0 + m * 16 + j) * N + ccol0 + n * 16] =
                        acc[m][n][j];
    }
}

extern "C" void kernel_launch(void* const* d_in, const int* in_sizes, int n_in,
                              void* d_out, int out_size, void* d_ws, size_t ws_size,
                              hipStream_t stream) {
    const float* values = (const float*)d_in[0];
    // d_in[1] = queries: only its length matters (Lq == L)
    const unsigned char* mask = (const unsigned char*)d_in[2];
    const float* Win  = (const float*)d_in[3];
    const float* Wout = (const float*)d_in[4];
    float* out = (float*)d_out;

    const int M = BATCH * SEQL;   // 8192
    const int N = EMB;            // 1024
    const int K = EMB;            // 1024

    u16* VG    = (u16*)d_ws;                              // 8*1056*1024 (17.3 MB)
    u16* Attb  = VG + (size_t)BATCH * VROWS * EMB;        // 16 MB
    u16* Winb  = Attb + (size_t)M * EMB;                  // 2 MB
    u16* Woutb = Winb + (size_t)EMB * EMB;                // 2 MB (~37 MB total)

    smooth_lds<<<1056 + 1024, 256, 0, stream>>>(
        values, mask, Win, Wout, VG, Winb, Woutb);

    dim3 ggrid((M / BM) * (N / BN));   // 64*8 = 512 WGs = 2 blocks/CU
    gemm_nt_pipe<true,  true ><<<ggrid, 256, 0, stream>>>(VG,   Winb,  Attb, M, N, K);
    gemm_nt_pipe<false, false><<<ggrid, 256, 0, stream>>>(Attb, Woutb, out,  M, N, K);
}

// Round 16
// 60.994 us; speedup vs baseline: 1.0342x; 1.0339x over previous
//
#include <hip/hip_runtime.h>
#include <hip/hip_bf16.h>
#include <cstddef>

// B=8, L=1024, E=1024, H=8, d=128
// out = BandedGaussianAttn(values @ Win^T) @ Wout^T
// Identity (R4..R13-proven): equal stds -> smoothing commutes with projection;
// per-head offset = row shift of GEMM1's A operand (BN=128 == one head).
// R16 = exact re-anchor of R13 (best measured config, 61.03 us):
//   smooth_lds: async-staged 9-tap smoother (fp32->bf16) + weight cvt
//   GEMM (R10/R13 structure): BM=256 BN=128 BK=64, 512thr/8waves (4Mx2N),
//     3-buffer LDS, 2 fine phases/K-tile, counted vmcnt(6), T2 XOR swizzle,
//     T5 setprio, T1 XCD swizzle.

#define BATCH 8
#define SEQL  1024
#define EMB   1024
#define VROWS 1056   // 33 x 32; VG row r holds smoothed source p = r-4

typedef unsigned short u16;
typedef __attribute__((ext_vector_type(8))) short s16x8;
typedef __attribute__((ext_vector_type(4))) float f32x4;
typedef __attribute__((ext_vector_type(8))) unsigned short u16x8;
typedef __attribute__((ext_vector_type(4))) unsigned short u16x4;

#define GLOAD_LDS16(g, l)                                                     \
    __builtin_amdgcn_global_load_lds(                                         \
        (const __attribute__((address_space(1))) void*)(g),                   \
        (__attribute__((address_space(3))) void*)(l), 16, 0, 0)

__device__ __forceinline__ u16 f2bf(float f) {
    unsigned u = __builtin_bit_cast(unsigned, f);
    u += 0x7FFF + ((u >> 16) & 1);
    return (u16)(u >> 16);
}

__constant__ int c_ofs[8] = { -3, -2, -1, 0, 0, 1, 2, 3 };

// ---------- smooth_lds: async-staged 9-tap smoother (R13-exact) ----------
__global__ __launch_bounds__(256) void smooth_lds(
    const float* __restrict__ values, const unsigned char* __restrict__ mask,
    const float* __restrict__ wi, const float* __restrict__ wo,
    u16* __restrict__ VG, u16* __restrict__ wib, u16* __restrict__ wob)
{
    constexpr float W[9] = {
        1.3383022576488537e-04f, 4.431848411938008e-03f, 5.399096651318806e-02f,
        2.4197072451914337e-01f, 3.989422804014327e-01f, 2.4197072451914337e-01f,
        5.399096651318806e-02f,  4.431848411938008e-03f, 1.3383022576488537e-04f
    };
    __shared__ float sx[40 * 256];
    __shared__ float smf[40];

    const int blk = blockIdx.x;
    const int NSM = BATCH * 33 * 4;    // 1056
    const int tid = threadIdx.x;
    if (blk < NSM) {
        const int b  = blk & 7;
        const int t  = blk >> 3;
        const int g  = t >> 2;
        const int cg = t & 3;
        const int r0 = g * 32;
        const int v0 = r0 - 8;
        const int c0 = cg * 256;
        const float* vbase = values + (size_t)b * SEQL * EMB + c0;
        const unsigned char* mrow = mask + b * SEQL;

        #pragma unroll
        for (int c = 0; c < 10; ++c) {
            const int n    = c * 256 + tid;
            const int row  = n >> 6;
            const int col4 = (n & 63) * 4;
            const int v    = v0 + row;
            const int vc   = v < 0 ? 0 : (v > SEQL - 1 ? SEQL - 1 : v);
            GLOAD_LDS16(vbase + (size_t)vc * EMB + col4,
                        sx + c * 1024 + (tid >> 6) * 256);
        }
        if (tid < 40) {
            const int v  = v0 + tid;
            const int vc = v < 0 ? 0 : (v > SEQL - 1 ? SEQL - 1 : v);
            smf[tid] = ((unsigned)v < (unsigned)SEQL && !mrow[vc]) ? 1.f : 0.f;
        }
        asm volatile("s_waitcnt vmcnt(0)" ::: "memory");
        __syncthreads();

        const int rg = tid >> 6;
        const int cc = tid & 63;
        const int rl0 = rg * 8;
        f32x4 acc[8] = {};
        #pragma unroll
        for (int i = 0; i < 16; ++i) {
            const f32x4 xr = *(const f32x4*)&sx[(rl0 + i) * 256 + cc * 4];
            const float f = smf[rl0 + i];
            const float x0 = xr[0] * f, x1 = xr[1] * f, x2 = xr[2] * f, x3 = xr[3] * f;
            #pragma unroll
            for (int k = 0; k < 8; ++k) {
                const int j = i - k;
                if (j < 0 || j > 8) continue;
                const float w = W[j];
                acc[k][0] = fmaf(w, x0, acc[k][0]);
                acc[k][1] = fmaf(w, x1, acc[k][1]);
                acc[k][2] = fmaf(w, x2, acc[k][2]);
                acc[k][3] = fmaf(w, x3, acc[k][3]);
            }
        }
        u16* og = VG + (size_t)(b * VROWS + r0 + rl0) * EMB + c0 + cc * 4;
        #pragma unroll
        for (int k = 0; k < 8; ++k) {
            u16x4 o;
            o[0] = f2bf(acc[k][0]); o[1] = f2bf(acc[k][1]);
            o[2] = f2bf(acc[k][2]); o[3] = f2bf(acc[k][3]);
            *(u16x4*)(og + (size_t)k * EMB) = o;
        }
    } else {
        const int k = (blk - NSM) * 256 + tid;
        const float* src = (k < 131072) ? wi : wo;
        u16* dst = (k < 131072) ? wib : wob;
        const size_t off = (size_t)(k & 131071) * 8;
        const float4 a = *(const float4*)(src + off);
        const float4 b4 = *(const float4*)(src + off + 4);
        u16x8 o;
        o[0] = f2bf(a.x);  o[1] = f2bf(a.y);  o[2] = f2bf(a.z);  o[3] = f2bf(a.w);
        o[4] = f2bf(b4.x); o[5] = f2bf(b4.y); o[6] = f2bf(b4.z); o[7] = f2bf(b4.w);
        *(u16x8*)(dst + off) = o;
    }
}

// ---------- pipelined bf16 MFMA GEMM: C[M,N] = A[M,K]*B[N,K]^T (R13-exact) ----------
constexpr int BM = 256, BN = 128, BK = 64;
constexpr int A_EL = BM * BK;
constexpr int B_EL = BN * BK;
constexpr int BUF_EL = A_EL + B_EL;      // 48 KB x3 = 144 KB

template <bool OUT_BF16, bool SHIFTED>
__global__ __launch_bounds__(512, 2) void gemm_nt_pipe(
    const u16* __restrict__ A, const u16* __restrict__ B,
    void* __restrict__ Cout, int M, int N, int K)
{
    __shared__ u16 lds[3 * BUF_EL];

    const int tid  = threadIdx.x;
    const int lane = tid & 63;
    const int wave = tid >> 6;

    const int nwg = gridDim.x;
    const int bid = blockIdx.x;
    const int swz = (bid & 7) * (nwg >> 3) + (bid >> 3);
    const int ntn = N >> 7;
    const int row0 = (swz / ntn) * BM;
    const int col0 = (swz % ntn) * BN;

    int arow0;
    if (SHIFTED) {
        const int b  = row0 >> 10;            // BM=256 | 1024: no batch straddle
        const int q0 = row0 & (SEQL - 1);
        arow0 = b * VROWS + q0 + 4 + c_ofs[col0 >> 7];
    } else {
        arow0 = row0;
    }
    const u16* Ab = A + (size_t)arow0 * K;
    const u16* Bb = B + (size_t)col0 * K;

    const int wm = wave >> 1;
    const int wn = wave & 1;
    const int fr = lane & 15;
    const int fg = lane >> 4;

    const int srow   = tid >> 3;
    const int schunk = tid & 7;

    f32x4 acc[4][4] = {};
    s16x8 af[4][2], bf0[2][2], bf1[2][2];

    auto stageA3 = [&](int bsel, int kt) {
        u16* Abuf = lds + bsel * BUF_EL;
        const int k0 = kt << 6;
        #pragma unroll
        for (int c = 0; c < 3; ++c) {
            const int row = c * 64 + srow;
            const int sc  = (schunk ^ (row & 7)) << 3;
            GLOAD_LDS16(Ab + (size_t)row * K + k0 + sc, Abuf + c * 4096 + wave * 512);
        }
    };
    auto stageRest = [&](int bsel, int kt) {
        u16* Abuf = lds + bsel * BUF_EL;
        u16* Bbuf = Abuf + A_EL;
        const int k0 = kt << 6;
        {
            const int row = 192 + srow;
            const int sc  = (schunk ^ (row & 7)) << 3;
            GLOAD_LDS16(Ab + (size_t)row * K + k0 + sc, Abuf + 3 * 4096 + wave * 512);
        }
        #pragma unroll
        for (int c = 0; c < 2; ++c) {
            const int row = c * 64 + srow;
            const int sc  = (schunk ^ (row & 7)) << 3;
            GLOAD_LDS16(Bb + (size_t)row * K + k0 + sc, Bbuf + c * 4096 + wave * 512);
        }
    };

    auto phase0 = [&](int tile, bool doStage) {
        const u16* Abuf = lds + (tile % 3) * BUF_EL;
        const u16* Bbuf = Abuf + A_EL;
        #pragma unroll
        for (int m = 0; m < 4; ++m)
            #pragma unroll
            for (int kk = 0; kk < 2; ++kk) {
                const int row = wm * 64 + m * 16 + fr;
                const int ch  = ((kk << 2) + fg) ^ (row & 7);
                af[m][kk] = *(const s16x8*)(Abuf + row * 64 + ch * 8);
            }
        #pragma unroll
        for (int n = 0; n < 2; ++n)
            #pragma unroll
            for (int kk = 0; kk < 2; ++kk) {
                const int row = wn * 64 + n * 16 + fr;
                const int ch  = ((kk << 2) + fg) ^ (row & 7);
                bf0[n][kk] = *(const s16x8*)(Bbuf + row * 64 + ch * 8);
            }
        if (doStage) stageA3((tile + 2) % 3, tile + 2);
        __builtin_amdgcn_s_barrier();
        asm volatile("s_waitcnt lgkmcnt(0)" ::: "memory");
        __builtin_amdgcn_sched_barrier(0);
        __builtin_amdgcn_s_setprio(1);
        #pragma unroll
        for (int m = 0; m < 4; ++m)
            #pragma unroll
            for (int n = 0; n < 2; ++n)
                #pragma unroll
                for (int kk = 0; kk < 2; ++kk)
                    acc[m][n] = __builtin_amdgcn_mfma_f32_16x16x32_bf16(
                        af[m][kk], bf0[n][kk], acc[m][n], 0, 0, 0);
        __builtin_amdgcn_s_setprio(0);
        __builtin_amdgcn_s_barrier();
    };

    auto phase1 = [&](int tile, int mode /*0: stage+vm6, 1: vm0, 2: none*/) {
        const u16* Abuf = lds + (tile % 3) * BUF_EL;
        const u16* Bbuf = Abuf + A_EL;
        #pragma unroll
        for (int n = 0; n < 2; ++n)
            #pragma unroll
            for (int kk = 0; kk < 2; ++kk) {
                const int row = wn * 64 + (2 + n) * 16 + fr;
                const int ch  = ((kk << 2) + fg) ^ (row & 7);
                bf1[n][kk] = *(const s16x8*)(Bbuf + row * 64 + ch * 8);
            }
        if (mode == 0) {
            stageRest((tile + 2) % 3, tile + 2);
            asm volatile("s_waitcnt vmcnt(6)" ::: "memory");
        } else if (mode == 1) {
            asm volatile("s_waitcnt vmcnt(0)" ::: "memory");
        }
        __builtin_amdgcn_s_barrier();
        asm volatile("s_waitcnt lgkmcnt(0)" ::: "memory");
        __builtin_amdgcn_sched_barrier(0);
        __builtin_amdgcn_s_setprio(1);
        #pragma unroll
        for (int m = 0; m < 4; ++m)
            #pragma unroll
            for (int n = 0; n < 2; ++n)
                #pragma unroll
                for (int kk = 0; kk < 2; ++kk)
                    acc[m][2 + n] = __builtin_amdgcn_mfma_f32_16x16x32_bf16(
                        af[m][kk], bf1[n][kk], acc[m][2 + n], 0, 0, 0);
        __builtin_amdgcn_s_setprio(0);
        __builtin_amdgcn_s_barrier();
    };

    const int NT = K >> 6;

    stageA3(0, 0); stageRest(0, 0);
    stageA3(1, 1); stageRest(1, 1);
    asm volatile("s_waitcnt vmcnt(6)" ::: "memory");
    __builtin_amdgcn_s_barrier();

    for (int t = 0; t < NT - 2; ++t) { phase0(t, true); phase1(t, 0); }
    phase0(NT - 2, false); phase1(NT - 2, 1);
    phase0(NT - 1, false); phase1(NT - 1, 2);

    const int crow0 = row0 + wm * 64 + fg * 4;
    const int ccol0 = col0 + wn * 64 + fr;
    if (OUT_BF16) {
        u16* C = (u16*)Cout;
        #pragma unroll
        for (int m = 0; m < 4; ++m)
            #pragma unroll
            for (int n = 0; n < 4; ++n)
                #pragma unroll
                for (int j = 0; j < 4; ++j)
                    C[(size_t)(crow0 + m * 16 + j) * N + ccol0 + n * 16] =
                        f2bf(acc[m][n][j]);
    } else {
        float* C = (float*)Cout;
        #pragma unroll
        for (int m = 0; m < 4; ++m)
            #pragma unroll
            for (int n = 0; n < 4; ++n)
                #pragma unroll
                for (int j = 0; j < 4; ++j)
                    C[(size_t)(crow0 + m * 16 + j) * N + ccol0 + n * 16] =
                        acc[m][n][j];
    }
}

extern "C" void kernel_launch(void* const* d_in, const int* in_sizes, int n_in,
                              void* d_out, int out_size, void* d_ws, size_t ws_size,
                              hipStream_t stream) {
    const float* values = (const float*)d_in[0];
    // d_in[1] = queries: only its length matters (Lq == L)
    const unsigned char* mask = (const unsigned char*)d_in[2];
    const float* Win  = (const float*)d_in[3];
    const float* Wout = (const float*)d_in[4];
    float* out = (float*)d_out;

    const int M = BATCH * SEQL;   // 8192
    const int N = EMB;            // 1024
    const int K = EMB;            // 1024

    u16* VG    = (u16*)d_ws;                              // 8*1056*1024 (17.3 MB)
    u16* Attb  = VG + (size_t)BATCH * VROWS * EMB;        // 16 MB
    u16* Winb  = Attb + (size_t)M * EMB;                  // 2 MB
    u16* Woutb = Winb + (size_t)EMB * EMB;                // 2 MB (~37 MB total)

    smooth_lds<<<1056 + 1024, 256, 0, stream>>>(
        values, mask, Win, Wout, VG, Winb, Woutb);

    dim3 ggrid((M / BM) * (N / BN));   // 256 WGs
    gemm_nt_pipe<true,  true ><<<ggrid, 512, 0, stream>>>(VG,   Winb,  Attb, M, N, K);
    gemm_nt_pipe<false, false><<<ggrid, 512, 0, stream>>>(Attb, Woutb, out,  M, N, K);
}